// Round 2
// baseline (481.504 us; speedup 1.0000x reference)
//
#include <hip/hip_runtime.h>
#include <hip/hip_bf16.h>

typedef unsigned short ushort_t;
typedef short bf16x8 __attribute__((ext_vector_type(8)));
typedef ushort_t u16x8 __attribute__((ext_vector_type(8)));
typedef float f32x4 __attribute__((ext_vector_type(4)));

#define DEV static __device__ __forceinline__

DEV float bf2f(ushort_t u) { unsigned v = ((unsigned)u) << 16; float f; __builtin_memcpy(&f, &v, 4); return f; }
DEV short f2bf(float x) { __hip_bfloat16 h = __float2bfloat16(x); short s; __builtin_memcpy(&s, &h, 2); return s; }
DEV float sigm(float x) { return 1.0f / (1.0f + __expf(-x)); }

// ---------------- K_detect: decide whether inputs are bf16 (flag=0) or fp32 (flag=1).
// bf16 N(0,1) data decodes to |v| < ~6; fp32 read as bf16 words yields wild exponents.
__global__ void k_detect(const ushort_t* __restrict__ hidden, int* __restrict__ flag,
                         float* __restrict__ scal, const void* stepp, const void* decayp) {
    __shared__ int bad;
    if (threadIdx.x == 0) bad = 0;
    __syncthreads();
    for (int i = threadIdx.x; i < 65536; i += 256) {
        float v = bf2f(hidden[i]);
        if (!(fabsf(v) < 100.f)) bad = 1;  // catches huge + inf + NaN
    }
    __syncthreads();
    if (threadIdx.x == 0) {
        *flag = bad;
        if (bad) {
            scal[0] = ((const float*)stepp)[0];
            scal[1] = ((const float*)decayp)[0];
        } else {
            scal[0] = bf2f(((const ushort_t*)stepp)[0]);
            scal[1] = bf2f(((const ushort_t*)decayp)[0]);
        }
    }
}

// ---------------- K_norm: normalize an input tensor to bf16 scratch (either passthrough or fp32->bf16)
__global__ void k_norm(const void* __restrict__ src, ushort_t* __restrict__ dst, int n,
                       const int* __restrict__ flag) {
    int i = blockIdx.x * 256 + threadIdx.x;
    if (i >= n) return;
    if (*flag) dst[i] = (ushort_t)f2bf(((const float*)src)[i]);
    else       dst[i] = ((const ushort_t*)src)[i];
}

// ---------------- K1b: FV[8192][128] = Hn[8192][1024] @ Wcat^T  (bf16 MFMA, fp32 out)
// Wcat rows 0..63 = W1, rows 64..127 = Wv.
__global__ __launch_bounds__(256) void k_fv(const ushort_t* __restrict__ h,
                                            const ushort_t* __restrict__ Wcat,
                                            float* __restrict__ FV) {
    int m0 = blockIdx.x * 128;
    int wave = threadIdx.x >> 6, lane = threadIdx.x & 63;
    int wm = wave >> 1, wn = wave & 1;
    int l16 = lane & 15, quad = lane >> 4;
    f32x4 acc[4][4] = {};
    int arow[4], brow[4];
#pragma unroll
    for (int f = 0; f < 4; f++) arow[f] = m0 + wm * 64 + f * 16 + l16;
#pragma unroll
    for (int f = 0; f < 4; f++) brow[f] = wn * 64 + f * 16 + l16;
    for (int kc = 0; kc < 1024; kc += 32) {
        int ko = kc + quad * 8;
        bf16x8 af[4], bf[4];
#pragma unroll
        for (int f = 0; f < 4; f++) af[f] = *reinterpret_cast<const bf16x8*>(h + arow[f] * 1024 + ko);
#pragma unroll
        for (int f = 0; f < 4; f++) bf[f] = *reinterpret_cast<const bf16x8*>(Wcat + brow[f] * 1024 + ko);
#pragma unroll
        for (int i = 0; i < 4; i++)
#pragma unroll
            for (int j = 0; j < 4; j++)
                acc[i][j] = __builtin_amdgcn_mfma_f32_16x16x32_bf16(af[i], bf[j], acc[i][j], 0, 0, 0);
    }
#pragma unroll
    for (int i = 0; i < 4; i++)
#pragma unroll
        for (int j = 0; j < 4; j++)
#pragma unroll
            for (int r = 0; r < 4; r++) {
                int row = m0 + wm * 64 + i * 16 + quad * 4 + r;
                int col = wn * 64 + j * 16 + l16;
                FV[row * 128 + col] = acc[i][j][r];
            }
}

// ---------------- K1c: per-row gelu -> features -> Q,K,charge0; zero received/Oacc
__global__ __launch_bounds__(256) void k_feat(const float* __restrict__ FV,
        const ushort_t* __restrict__ b1, const ushort_t* __restrict__ W2, const ushort_t* __restrict__ b2,
        const ushort_t* __restrict__ Wq, const ushort_t* __restrict__ Wk,
        const ushort_t* __restrict__ Wc, const ushort_t* __restrict__ bc,
        ushort_t* __restrict__ Qb, ushort_t* __restrict__ Kb,
        float* __restrict__ charges, float* __restrict__ received, float* __restrict__ Oacc) {
    __shared__ float w2L[28 * 65], wqL[64 * 29], wkL[64 * 29], wcL[28], b2L[28];
    __shared__ float fL[4][64], featL[4][28];
    int tid = threadIdx.x;
    for (int i = tid; i < 28 * 64; i += 256) w2L[(i >> 6) * 65 + (i & 63)] = bf2f(W2[i]);
    for (int i = tid; i < 64 * 28; i += 256) {
        int r = i / 28, c = i - r * 28;
        wqL[r * 29 + c] = bf2f(Wq[i]);
        wkL[r * 29 + c] = bf2f(Wk[i]);
    }
    if (tid < 28) { wcL[tid] = bf2f(Wc[tid]); b2L[tid] = bf2f(b2[tid]); }
    __syncthreads();
    int w = tid >> 6, lane = tid & 63;
    int row = blockIdx.x * 4 + w;
    float x = FV[row * 128 + lane] + bf2f(b1[lane]);
    fL[w][lane] = 0.5f * x * (1.0f + erff(x * 0.70710678118654752f));
    __syncthreads();
    if (lane < 28) {
        float s = b2L[lane];
#pragma unroll
        for (int j = 0; j < 64; j++) s += fL[w][j] * w2L[lane * 65 + j];
        featL[w][lane] = sigm(s);
    }
    __syncthreads();
    float q = 0.f, k = 0.f;
#pragma unroll
    for (int i = 0; i < 28; i++) {
        float fv = featL[w][i];
        q += fv * wqL[lane * 29 + i];
        k += fv * wkL[lane * 29 + i];
    }
    Qb[row * 64 + lane] = (ushort_t)f2bf(q * 0.125f);  // fold 1/sqrt(64)
    Kb[row * 64 + lane] = (ushort_t)f2bf(k);
    Oacc[row * 64 + lane] = 0.f;
    if (lane == 0) {
        float c = bf2f(bc[0]);
#pragma unroll
        for (int i = 0; i < 28; i++) c += featL[w][i] * wcL[i];
        charges[row] = sigm(c);
        received[row] = 0.f;
    }
}

// ---------------- K1d: VbT[64][8192] = transpose(FV[:,64:128]) as bf16
__global__ __launch_bounds__(256) void k_vbt(const float* __restrict__ FV, ushort_t* __restrict__ VbT) {
    __shared__ float tL[64][65];
    int r0 = blockIdx.x * 64;
    for (int i = threadIdx.x; i < 64 * 64; i += 256) {
        int r = i >> 6, d = i & 63;
        tL[r][d] = FV[(r0 + r) * 128 + 64 + d];
    }
    __syncthreads();
    for (int i = threadIdx.x; i < 64 * 64; i += 256) {
        int d = i >> 6, r = i & 63;
        VbT[d * 8192 + r0 + r] = (ushort_t)f2bf(tL[r][d]);
    }
}

DEV void tri_decode(int r, int& ti, int& tj) {
    int t = (int)((sqrtf(8.f * (float)r + 1.f) - 1.f) * 0.5f);
    while ((t + 1) * (t + 2) / 2 <= r) t++;
    while (t * (t + 1) / 2 > r) t--;
    ti = t;
    tj = r - t * (t + 1) / 2;
}

// ---------------- K2: compat[(b*2048+n)][m] = (Q/8)·K for causal 128x128 tiles; bf16 store
__global__ __launch_bounds__(256) void k_compat(const ushort_t* __restrict__ Qb,
                                                const ushort_t* __restrict__ Kb,
                                                ushort_t* __restrict__ compat) {
    int bid = blockIdx.x;
    int b = bid / 136, r = bid % 136, ti, tj;
    tri_decode(r, ti, tj);
    int wave = threadIdx.x >> 6, lane = threadIdx.x & 63;
    int l16 = lane & 15, quad = lane >> 4;
    int rbase = b * 2048 + ti * 128 + wave * 32;  // global row id
    int cbase = b * 2048 + tj * 128;              // global col id into Kb
    f32x4 acc[2][8] = {};
#pragma unroll
    for (int kc = 0; kc < 64; kc += 32) {
        int ko = kc + quad * 8;
        bf16x8 af[2], bf[8];
#pragma unroll
        for (int f = 0; f < 2; f++) af[f] = *reinterpret_cast<const bf16x8*>(Qb + (rbase + f * 16 + l16) * 64 + ko);
#pragma unroll
        for (int f = 0; f < 8; f++) bf[f] = *reinterpret_cast<const bf16x8*>(Kb + (cbase + f * 16 + l16) * 64 + ko);
#pragma unroll
        for (int i = 0; i < 2; i++)
#pragma unroll
            for (int j = 0; j < 8; j++)
                acc[i][j] = __builtin_amdgcn_mfma_f32_16x16x32_bf16(af[i], bf[j], acc[i][j], 0, 0, 0);
    }
    int colt = tj * 128;
#pragma unroll
    for (int i = 0; i < 2; i++)
#pragma unroll
        for (int j = 0; j < 8; j++)
#pragma unroll
            for (int rr = 0; rr < 4; rr++) {
                long rowg = rbase + i * 16 + quad * 4 + rr;
                int col = colt + j * 16 + l16;
                compat[rowg * 2048 + col] = (ushort_t)f2bf(acc[i][j][rr]);
            }
}

// ---------------- pass A: per-row max & sumexp of logits_T (sigma has T charge terms)
template <int T>
__global__ __launch_bounds__(256) void k_rowstats(const ushort_t* __restrict__ compat,
        const float* __restrict__ charges, const float* __restrict__ scal,
        float* __restrict__ Mrow, float* __restrict__ Lrow) {
    int wave = threadIdx.x >> 6, lane = threadIdx.x & 63;
    int id = blockIdx.x * 4 + wave;   // global row id
    int n = id & 2047;
    int colbase = id & ~2047;
    float step = scal[0];
    float rowf[T > 0 ? T : 1];
#pragma unroll
    for (int s = 0; s < T; s++) rowf[s] = step * charges[(s + 1) * 8192 + id];
    const ushort_t* crow = compat + (long)id * 2048;
    float M = -1e30f, S = 0.f;
    for (int m = lane; m <= n; m += 64) {
        float c = bf2f(crow[m]);
        float sg = 1.f;
#pragma unroll
        for (int s = 0; s < T; s++) sg += rowf[s] * charges[(s + 1) * 8192 + colbase + m];
        float x = fminf(fmaxf(c * sg, -80.f), 80.f);
        if (x > M) { S = S * __expf(M - x) + 1.f; M = x; }
        else S += __expf(x - M);
    }
#pragma unroll
    for (int off = 32; off > 0; off >>= 1) {
        float M2 = __shfl_down(M, off);
        float S2 = __shfl_down(S, off);
        float Mn = fmaxf(M, M2);
        S = S * __expf(M - Mn) + S2 * __expf(M2 - Mn);
        M = Mn;
    }
    if (lane == 0) { Mrow[id] = M; Lrow[id] = fmaxf(S, 1e-30f); }
}

// ---------------- pass B: received[m] += sum_n attn[n][m]  (causal tiles, LDS partials + atomics)
template <int T>
__global__ __launch_bounds__(256) void k_colsum(const ushort_t* __restrict__ compat,
        const float* __restrict__ charges, const float* __restrict__ scal,
        const float* __restrict__ Mrow, const float* __restrict__ Lrow,
        float* __restrict__ received) {
    __shared__ float sums[128];
    int bid = blockIdx.x;
    int b = bid / 136, r = bid % 136, ti, tj;
    tri_decode(r, ti, tj);
    int tid = threadIdx.x;
    int ml = tid & 127, half = tid >> 7;
    int m = tj * 128 + ml;
    int mid = b * 2048 + m;
    float step = scal[0];
    float cm[T > 0 ? T : 1];
#pragma unroll
    for (int s = 0; s < T; s++) cm[s] = charges[(s + 1) * 8192 + mid];
    float acc = 0.f;
    bool diag = (ti == tj);
    for (int nl = half; nl < 128; nl += 2) {
        int n = ti * 128 + nl;
        int nid = b * 2048 + n;
        float Mr = Mrow[nid];
        float Li = 1.0f / Lrow[nid];
        float sg = 1.f;
#pragma unroll
        for (int s = 0; s < T; s++) sg += step * charges[(s + 1) * 8192 + nid] * cm[s];
        float c = bf2f(compat[(long)nid * 2048 + m]);
        float e = fminf(c * sg - Mr, 80.f);
        float p = __expf(e) * Li;
        if (!diag || m <= n) acc += p;
    }
    if (half == 0) sums[ml] = acc;
    __syncthreads();
    if (half == 1) sums[ml] += acc;
    __syncthreads();
    if (tid < 128) atomicAdd(&received[b * 2048 + tj * 128 + tid], sums[tid]);
}

// ---------------- charge update (also re-zeroes received for the next pass)
__global__ void k_charge(float* __restrict__ received, float* __restrict__ charges,
                         const float* __restrict__ scal, int t) {
    int i = blockIdx.x * 256 + threadIdx.x;
    if (i >= 8192) return;
    float decay = scal[1];
    float rcv = received[i];
    float sg = 1.0f / (1.0f + __expf(1.0f - rcv));
    charges[t * 8192 + i] = charges[(t - 1) * 8192 + i] * (1.f - decay * sg);
    received[i] = 0.f;
}

// ---------------- final PV: Oacc[n][d] += sum_m p(n,m)*V[m][d]  (MFMA, stats precomputed)
__global__ __launch_bounds__(256) void k_pv(const ushort_t* __restrict__ compat,
        const float* __restrict__ charges, const float* __restrict__ scal,
        const float* __restrict__ Mrow, const float* __restrict__ Lrow,
        const ushort_t* __restrict__ VbT, float* __restrict__ Oacc) {
    int bid = blockIdx.x;
    int b = bid / 144, r = bid % 144;
    int rt = 0, acc0 = 0;
    while (acc0 + (rt >> 2) + 1 <= r) { acc0 += (rt >> 2) + 1; rt++; }
    int seg = r - acc0;
    int wave = threadIdx.x >> 6, lane = threadIdx.x & 63;
    int l16 = lane & 15, quad = lane >> 4;
    int rowl = rt * 64 + wave * 16 + l16;  // n within batch (A-frag row)
    int rid = b * 2048 + rowl;
    float step = scal[0];
    float rowf[4];
#pragma unroll
    for (int s = 0; s < 4; s++) rowf[s] = step * charges[(s + 1) * 8192 + rid];
    float Mr = Mrow[rid];
    float Li = 1.0f / Lrow[rid];
    const ushort_t* crow = compat + (long)rid * 2048;
    int mstart = seg * 256;
    int mend = min(mstart + 256, rt * 64 + 64);
    f32x4 acc[4] = {};
    for (int mb = mstart; mb < mend; mb += 32) {
        int mk = mb + quad * 8;
        u16x8 cv = *reinterpret_cast<const u16x8*>(crow + mk);
        float ch[4][8];
#pragma unroll
        for (int s = 0; s < 4; s++) {
            const float* cp = charges + (s + 1) * 8192 + b * 2048 + mk;
            float4 a0 = *reinterpret_cast<const float4*>(cp);
            float4 a1 = *reinterpret_cast<const float4*>(cp + 4);
            ch[s][0] = a0.x; ch[s][1] = a0.y; ch[s][2] = a0.z; ch[s][3] = a0.w;
            ch[s][4] = a1.x; ch[s][5] = a1.y; ch[s][6] = a1.z; ch[s][7] = a1.w;
        }
        bf16x8 pf;
#pragma unroll
        for (int j = 0; j < 8; j++) {
            int m = mk + j;
            float sg = 1.f;
#pragma unroll
            for (int s = 0; s < 4; s++) sg += rowf[s] * ch[s][j];
            float e = fminf(bf2f(cv[j]) * sg - Mr, 80.f);
            float p = (m <= rowl) ? __expf(e) * Li : 0.f;
            pf[j] = f2bf(p);
        }
        bf16x8 vf[4];
#pragma unroll
        for (int f = 0; f < 4; f++)
            vf[f] = *reinterpret_cast<const bf16x8*>(VbT + (f * 16 + l16) * 8192 + b * 2048 + mk);
#pragma unroll
        for (int f = 0; f < 4; f++)
            acc[f] = __builtin_amdgcn_mfma_f32_16x16x32_bf16(pf, vf[f], acc[f], 0, 0, 0);
    }
#pragma unroll
    for (int f = 0; f < 4; f++)
#pragma unroll
        for (int rr = 0; rr < 4; rr++) {
            int rowg = b * 2048 + rt * 64 + wave * 16 + quad * 4 + rr;
            atomicAdd(&Oacc[rowg * 64 + f * 16 + l16], acc[f][rr]);
        }
}

// ---------------- out = (Oacc @ Wo^T) * 0.1, store per detected dtype
__global__ __launch_bounds__(256) void k_oproj(const float* __restrict__ Oacc,
                                               const ushort_t* __restrict__ Wo,
                                               void* __restrict__ out,
                                               const int* __restrict__ flag) {
    int mt = blockIdx.x & 63, nt = blockIdx.x >> 6;
    int wave = threadIdx.x >> 6, lane = threadIdx.x & 63;
    int wm = wave >> 1, wn = wave & 1;
    int l16 = lane & 15, quad = lane >> 4;
    int row0 = mt * 128 + wm * 64;
    int col0 = nt * 128 + wn * 64;
    f32x4 acc[4][4] = {};
#pragma unroll
    for (int kc = 0; kc < 64; kc += 32) {
        int ko = kc + quad * 8;
        bf16x8 af[4], bfm[4];
#pragma unroll
        for (int f = 0; f < 4; f++) {
            const float* ap = Oacc + (row0 + f * 16 + l16) * 64 + ko;
            float4 a0 = *reinterpret_cast<const float4*>(ap);
            float4 a1 = *reinterpret_cast<const float4*>(ap + 4);
            bf16x8 t;
            t[0] = f2bf(a0.x); t[1] = f2bf(a0.y); t[2] = f2bf(a0.z); t[3] = f2bf(a0.w);
            t[4] = f2bf(a1.x); t[5] = f2bf(a1.y); t[6] = f2bf(a1.z); t[7] = f2bf(a1.w);
            af[f] = t;
        }
#pragma unroll
        for (int f = 0; f < 4; f++)
            bfm[f] = *reinterpret_cast<const bf16x8*>(Wo + (col0 + f * 16 + l16) * 64 + ko);
#pragma unroll
        for (int i = 0; i < 4; i++)
#pragma unroll
            for (int j = 0; j < 4; j++)
                acc[i][j] = __builtin_amdgcn_mfma_f32_16x16x32_bf16(af[i], bfm[j], acc[i][j], 0, 0, 0);
    }
    int fp32mode = *flag;
#pragma unroll
    for (int i = 0; i < 4; i++)
#pragma unroll
        for (int j = 0; j < 4; j++)
#pragma unroll
            for (int rr = 0; rr < 4; rr++) {
                long rowg = row0 + i * 16 + quad * 4 + rr;
                int colg = col0 + j * 16 + l16;
                float v = acc[i][j][rr] * 0.1f;
                if (fp32mode) ((float*)out)[rowg * 1024 + colg] = v;
                else ((ushort_t*)out)[rowg * 1024 + colg] = (ushort_t)f2bf(v);
            }
}

extern "C" void kernel_launch(void* const* d_in, const int* in_sizes, int n_in,
                              void* d_out, int out_size, void* d_ws, size_t ws_size,
                              hipStream_t stream) {
    char* ws = (char*)d_ws;
    size_t off = 0;
    auto alloc = [&](size_t bytes) {
        void* p = ws + off;
        off += (bytes + 255) & ~(size_t)255;
        return p;
    };
    ushort_t* compat = (ushort_t*)alloc(8192UL * 2048 * 2);  // 32 MiB (bf16)
    ushort_t* Hn = (ushort_t*)alloc(8192UL * 1024 * 2);      // 16 MiB
    float* FV = (float*)alloc(8192UL * 128 * 4);             // 4 MiB
    ushort_t* Wcat = (ushort_t*)alloc(128UL * 1024 * 2);
    ushort_t* Qb = (ushort_t*)alloc(8192UL * 64 * 2);
    ushort_t* Kb = (ushort_t*)alloc(8192UL * 64 * 2);
    ushort_t* VbT = (ushort_t*)alloc(64UL * 8192 * 2);
    float* Oacc = (float*)alloc(8192UL * 64 * 4);
    float* charges = (float*)alloc(5UL * 8192 * 4);
    float* Mrow = (float*)alloc(8192UL * 4);
    float* Lrow = (float*)alloc(8192UL * 4);
    float* received = (float*)alloc(8192UL * 4);
    ushort_t* b1n = (ushort_t*)alloc(64 * 2);
    ushort_t* W2n = (ushort_t*)alloc(28 * 64 * 2);
    ushort_t* b2n = (ushort_t*)alloc(28 * 2);
    ushort_t* Wqn = (ushort_t*)alloc(64 * 28 * 2);
    ushort_t* Wkn = (ushort_t*)alloc(64 * 28 * 2);
    ushort_t* Wcn = (ushort_t*)alloc(28 * 2);
    ushort_t* bcn = (ushort_t*)alloc(2);
    ushort_t* Won = (ushort_t*)alloc(1024UL * 64 * 2);
    int* flag = (int*)alloc(4);
    float* scal = (float*)alloc(2 * 4);
    (void)ws_size; (void)in_sizes; (void)n_in; (void)out_size;

    // dtype detection + input normalization to bf16
    k_detect<<<1, 256, 0, stream>>>((const ushort_t*)d_in[0], flag, scal, d_in[11], d_in[12]);
    k_norm<<<32768, 256, 0, stream>>>(d_in[0], Hn, 8192 * 1024, flag);
    k_norm<<<256, 256, 0, stream>>>(d_in[1], Wcat, 64 * 1024, flag);            // W1 -> rows 0..63
    k_norm<<<256, 256, 0, stream>>>(d_in[9], Wcat + 64 * 1024, 64 * 1024, flag); // Wv -> rows 64..127
    k_norm<<<1, 256, 0, stream>>>(d_in[2], b1n, 64, flag);
    k_norm<<<7, 256, 0, stream>>>(d_in[3], W2n, 28 * 64, flag);
    k_norm<<<1, 256, 0, stream>>>(d_in[4], b2n, 28, flag);
    k_norm<<<7, 256, 0, stream>>>(d_in[5], Wqn, 64 * 28, flag);
    k_norm<<<7, 256, 0, stream>>>(d_in[6], Wkn, 64 * 28, flag);
    k_norm<<<1, 256, 0, stream>>>(d_in[7], Wcn, 28, flag);
    k_norm<<<1, 256, 0, stream>>>(d_in[8], bcn, 1, flag);
    k_norm<<<256, 256, 0, stream>>>(d_in[10], Won, 1024 * 64, flag);

    k_fv<<<64, 256, 0, stream>>>(Hn, Wcat, FV);
    k_feat<<<2048, 256, 0, stream>>>(FV, b1n, W2n, b2n, Wqn, Wkn, Wcn, bcn, Qb, Kb, charges, received, Oacc);
    k_vbt<<<128, 256, 0, stream>>>(FV, VbT);
    k_compat<<<544, 256, 0, stream>>>(Qb, Kb, compat);

    // iteration 1..4: rowstats(sigma_{t-1}) -> colsum -> charge update
    k_rowstats<0><<<2048, 256, 0, stream>>>(compat, charges, scal, Mrow, Lrow);
    k_colsum<0><<<544, 256, 0, stream>>>(compat, charges, scal, Mrow, Lrow, received);
    k_charge<<<32, 256, 0, stream>>>(received, charges, scal, 1);

    k_rowstats<1><<<2048, 256, 0, stream>>>(compat, charges, scal, Mrow, Lrow);
    k_colsum<1><<<544, 256, 0, stream>>>(compat, charges, scal, Mrow, Lrow, received);
    k_charge<<<32, 256, 0, stream>>>(received, charges, scal, 2);

    k_rowstats<2><<<2048, 256, 0, stream>>>(compat, charges, scal, Mrow, Lrow);
    k_colsum<2><<<544, 256, 0, stream>>>(compat, charges, scal, Mrow, Lrow, received);
    k_charge<<<32, 256, 0, stream>>>(received, charges, scal, 3);

    k_rowstats<3><<<2048, 256, 0, stream>>>(compat, charges, scal, Mrow, Lrow);
    k_colsum<3><<<544, 256, 0, stream>>>(compat, charges, scal, Mrow, Lrow, received);
    k_charge<<<32, 256, 0, stream>>>(received, charges, scal, 4);

    // final softmax stats + PV + output projection
    k_rowstats<4><<<2048, 256, 0, stream>>>(compat, charges, scal, Mrow, Lrow);
    k_pv<<<576, 256, 0, stream>>>(compat, charges, scal, Mrow, Lrow, VbT, Oacc);
    k_oproj<<<512, 256, 0, stream>>>(Oacc, Won, d_out, flag);
}

// Round 4
// 440.582 us; speedup vs baseline: 1.0929x; 1.0929x over previous
//
#include <hip/hip_runtime.h>
#include <hip/hip_bf16.h>

typedef unsigned short ushort_t;
typedef short bf16x8 __attribute__((ext_vector_type(8)));
typedef ushort_t u16x8 __attribute__((ext_vector_type(8)));
typedef float f32x4 __attribute__((ext_vector_type(4)));

#define DEV static __device__ __forceinline__

DEV float bf2f(ushort_t u) { unsigned v = ((unsigned)u) << 16; float f; __builtin_memcpy(&f, &v, 4); return f; }
DEV short f2bf(float x) { __hip_bfloat16 h = __float2bfloat16(x); short s; __builtin_memcpy(&s, &h, 2); return s; }
DEV float sigm(float x) { return 1.0f / (1.0f + __expf(-x)); }

// load 8 consecutive fp32 and convert to a bf16x8 MFMA fragment
DEV bf16x8 ld8f(const float* __restrict__ p) {
    float4 a0 = *reinterpret_cast<const float4*>(p);
    float4 a1 = *reinterpret_cast<const float4*>(p + 4);
    bf16x8 t;
    t[0] = f2bf(a0.x); t[1] = f2bf(a0.y); t[2] = f2bf(a0.z); t[3] = f2bf(a0.w);
    t[4] = f2bf(a1.x); t[5] = f2bf(a1.y); t[6] = f2bf(a1.z); t[7] = f2bf(a1.w);
    return t;
}

// ---------------- K1: 16-row tiles: Ff[8192][64] = hidden@W1^T (fp32), VbT[64][8192] = (hidden@Wv^T)^T bf16
// waves 0,1 -> W1 cols 0..31 / 32..63 (Ff); waves 2,3 -> Wv (VbT)
__global__ __launch_bounds__(256) void k_fv(const float* __restrict__ h,
        const float* __restrict__ W1, const float* __restrict__ Wv,
        float* __restrict__ Ff, ushort_t* __restrict__ VbT) {
    int m0 = blockIdx.x * 16;
    int wave = threadIdx.x >> 6, lane = threadIdx.x & 63;
    int l16 = lane & 15, quad = lane >> 4;
    const float* B = (wave < 2) ? W1 : Wv;
    int cb = (wave & 1) * 32;
    f32x4 acc[2] = {};
    const float* arow = h + (long)(m0 + l16) * 1024;
    const float* brow0 = B + (long)(cb + l16) * 1024;
    const float* brow1 = B + (long)(cb + 16 + l16) * 1024;
    for (int kc = 0; kc < 1024; kc += 32) {
        int ko = kc + quad * 8;
        bf16x8 af = ld8f(arow + ko);
        bf16x8 b0 = ld8f(brow0 + ko);
        bf16x8 b1v = ld8f(brow1 + ko);
        acc[0] = __builtin_amdgcn_mfma_f32_16x16x32_bf16(af, b0, acc[0], 0, 0, 0);
        acc[1] = __builtin_amdgcn_mfma_f32_16x16x32_bf16(af, b1v, acc[1], 0, 0, 0);
    }
    bool isV = (wave >= 2);
#pragma unroll
    for (int c = 0; c < 2; c++)
#pragma unroll
        for (int rr = 0; rr < 4; rr++) {
            int row = m0 + quad * 4 + rr;
            int col = cb + c * 16 + l16;
            float v = acc[c][rr];
            if (!isV) Ff[row * 64 + col] = v;
            else VbT[(long)col * 8192 + row] = (ushort_t)f2bf(v);
        }
}

// ---------------- K2: gelu -> features -> Q,K,charge0; zero received. 256 blocks x 32 rows.
__global__ __launch_bounds__(256) void k_feat(const float* __restrict__ Ff,
        const float* __restrict__ b1, const float* __restrict__ W2, const float* __restrict__ b2,
        const float* __restrict__ Wq, const float* __restrict__ Wk,
        const float* __restrict__ Wc, const float* __restrict__ bc,
        ushort_t* __restrict__ Qb, ushort_t* __restrict__ Kb,
        float* __restrict__ charge0, float* __restrict__ received) {
    __shared__ float w2L[28 * 65], wqL[64 * 29], wkL[64 * 29], wcL[28], b2L[28];
    __shared__ float fL[4][64], featL[4][28];
    int tid = threadIdx.x;
    for (int i = tid; i < 28 * 64; i += 256) w2L[(i >> 6) * 65 + (i & 63)] = W2[i];
    for (int i = tid; i < 64 * 28; i += 256) {
        int r = i / 28, c = i - r * 28;
        wqL[r * 29 + c] = Wq[i];
        wkL[r * 29 + c] = Wk[i];
    }
    if (tid < 28) { wcL[tid] = Wc[tid]; b2L[tid] = b2[tid]; }
    __syncthreads();
    int w = tid >> 6, lane = tid & 63;
    float b1v = b1[lane];
    float bcv = bc[0];
    for (int it = 0; it < 8; it++) {
        int row = blockIdx.x * 32 + it * 4 + w;
        float x = Ff[row * 64 + lane] + b1v;
        fL[w][lane] = 0.5f * x * (1.0f + erff(x * 0.70710678118654752f));
        __syncthreads();
        if (lane < 28) {
            float s = b2L[lane];
#pragma unroll
            for (int j = 0; j < 64; j++) s += fL[w][j] * w2L[lane * 65 + j];
            featL[w][lane] = sigm(s);
        }
        __syncthreads();
        float q = 0.f, k = 0.f;
#pragma unroll
        for (int i = 0; i < 28; i++) {
            float fv = featL[w][i];
            q += fv * wqL[lane * 29 + i];
            k += fv * wkL[lane * 29 + i];
        }
        Qb[row * 64 + lane] = (ushort_t)f2bf(q * 0.125f);  // fold 1/sqrt(64)
        Kb[row * 64 + lane] = (ushort_t)f2bf(k);
        if (lane == 0) {
            float c = bcv;
#pragma unroll
            for (int i = 0; i < 28; i++) c += featL[w][i] * wcL[i];
            charge0[row] = sigm(c);
            received[row] = 0.f;
        }
        __syncthreads();
    }
}

DEV void tri_decode(int r, int& ti, int& tj) {
    int t = (int)((sqrtf(8.f * (float)r + 1.f) - 1.f) * 0.5f);
    while ((t + 1) * (t + 2) / 2 <= r) t++;
    while (t * (t + 1) / 2 > r) t--;
    ti = t;
    tj = r - t * (t + 1) / 2;
}

// ---------------- K3: compat[(b*2048+n)][m] = (Q/8)·K, causal 128x128 tiles, bf16 store
__global__ __launch_bounds__(256) void k_compat(const ushort_t* __restrict__ Qb,
                                                const ushort_t* __restrict__ Kb,
                                                ushort_t* __restrict__ compat) {
    int bid = blockIdx.x;
    int b = bid / 136, r = bid % 136, ti, tj;
    tri_decode(r, ti, tj);
    int wave = threadIdx.x >> 6, lane = threadIdx.x & 63;
    int l16 = lane & 15, quad = lane >> 4;
    int rbase = b * 2048 + ti * 128 + wave * 32;
    int cbase = b * 2048 + tj * 128;
    f32x4 acc[2][8] = {};
#pragma unroll
    for (int kc = 0; kc < 64; kc += 32) {
        int ko = kc + quad * 8;
        bf16x8 af[2], bf[8];
#pragma unroll
        for (int f = 0; f < 2; f++) af[f] = *reinterpret_cast<const bf16x8*>(Qb + (long)(rbase + f * 16 + l16) * 64 + ko);
#pragma unroll
        for (int f = 0; f < 8; f++) bf[f] = *reinterpret_cast<const bf16x8*>(Kb + (long)(cbase + f * 16 + l16) * 64 + ko);
#pragma unroll
        for (int i = 0; i < 2; i++)
#pragma unroll
            for (int j = 0; j < 8; j++)
                acc[i][j] = __builtin_amdgcn_mfma_f32_16x16x32_bf16(af[i], bf[j], acc[i][j], 0, 0, 0);
    }
    int colt = tj * 128;
#pragma unroll
    for (int i = 0; i < 2; i++)
#pragma unroll
        for (int j = 0; j < 8; j++)
#pragma unroll
            for (int rr = 0; rr < 4; rr++) {
                long rowg = rbase + i * 16 + quad * 4 + rr;
                int col = colt + j * 16 + l16;
                compat[rowg * 2048 + col] = (ushort_t)f2bf(acc[i][j][rr]);
            }
}

// ---------------- pass A: Lrow[n] = sum_m<=n exp(compat*sigma)  (args bounded << 88, no max needed)
template <int T>
__global__ __launch_bounds__(256) void k_rowstats(const ushort_t* __restrict__ compat,
        const float4* __restrict__ charges4, const float* __restrict__ stepp,
        float* __restrict__ Lrow) {
    int wave = threadIdx.x >> 6, lane = threadIdx.x & 63;
    int id = blockIdx.x * 4 + wave;
    int n = id & 2047;
    int colbase = id & ~2047;
    float step = stepp[0];
    float rx = 0.f, ry = 0.f, rz = 0.f, rw = 0.f;
    if (T > 0) {
        float4 c4 = charges4[id];
        rx = step * c4.x;
        if (T > 1) ry = step * c4.y;
        if (T > 2) rz = step * c4.z;
        if (T > 3) rw = step * c4.w;
    }
    const ushort_t* crow = compat + (long)id * 2048;
    float S = 0.f;
    for (int m = lane; m <= n; m += 64) {
        float c = bf2f(crow[m]);
        float sg = 1.f;
        if (T > 0) {
            float4 ch = charges4[colbase + m];
            sg += rx * ch.x;
            if (T > 1) sg += ry * ch.y;
            if (T > 2) sg += rz * ch.z;
            if (T > 3) sg += rw * ch.w;
        }
        S += __expf(c * sg);
    }
#pragma unroll
    for (int off = 32; off > 0; off >>= 1) S += __shfl_down(S, off);
    if (lane == 0) Lrow[id] = fmaxf(S, 1e-30f);
}

// ---------------- pass B: received[m] += sum_n attn[n][m]
template <int T>
__global__ __launch_bounds__(256) void k_colsum(const ushort_t* __restrict__ compat,
        const float4* __restrict__ charges4, const float* __restrict__ stepp,
        const float* __restrict__ Lrow, float* __restrict__ received) {
    __shared__ float sums[128];
    int bid = blockIdx.x;
    int b = bid / 136, r = bid % 136, ti, tj;
    tri_decode(r, ti, tj);
    int tid = threadIdx.x;
    int ml = tid & 127, half = tid >> 7;
    int m = tj * 128 + ml;
    int mid = b * 2048 + m;
    float step = stepp[0];
    float cx = 0.f, cy = 0.f, cz = 0.f, cw = 0.f;
    if (T > 0) {
        float4 cm = charges4[mid];
        cx = step * cm.x;
        if (T > 1) cy = step * cm.y;
        if (T > 2) cz = step * cm.z;
        if (T > 3) cw = step * cm.w;
    }
    float acc = 0.f;
    bool diag = (ti == tj);
    for (int nl = half; nl < 128; nl += 2) {
        int n = ti * 128 + nl;
        int nid = b * 2048 + n;
        float Li = 1.0f / Lrow[nid];
        float sg = 1.f;
        if (T > 0) {
            float4 cn = charges4[nid];
            sg += cx * cn.x;
            if (T > 1) sg += cy * cn.y;
            if (T > 2) sg += cz * cn.z;
            if (T > 3) sg += cw * cn.w;
        }
        float c = bf2f(compat[(long)nid * 2048 + m]);
        float p = __expf(c * sg) * Li;
        if (!diag || m <= n) acc += p;
    }
    if (half == 0) sums[ml] = acc;
    __syncthreads();
    if (half == 1) sums[ml] += acc;
    __syncthreads();
    if (tid < 128) atomicAdd(&received[b * 2048 + tj * 128 + tid], sums[tid]);
}

// ---------------- charge update t (writes charges4 component T-1; re-zeroes received)
template <int T>
__global__ void k_charge(float* __restrict__ received, const float* __restrict__ charge0,
                         float4* __restrict__ charges4, const float* __restrict__ decayp) {
    int i = blockIdx.x * 256 + threadIdx.x;
    if (i >= 8192) return;
    float decay = decayp[0];
    float rcv = received[i];
    float sg = 1.0f / (1.0f + __expf(1.0f - rcv));
    float prev = (T == 1) ? charge0[i] : ((const float*)&charges4[i])[T - 2];
    ((float*)&charges4[i])[T - 1] = prev * (1.f - decay * sg);
    received[i] = 0.f;
}

// ---------------- final attention + PV, self-normalizing
__global__ __launch_bounds__(256) void k_pv(const ushort_t* __restrict__ compat,
        const float4* __restrict__ charges4, const float* __restrict__ stepp,
        const ushort_t* __restrict__ VbT, float* __restrict__ Oacc) {
    __shared__ float sL[4][16];
    int bid = blockIdx.x;
    int b = bid >> 5, rt = bid & 31;
    int w = threadIdx.x >> 6, lane = threadIdx.x & 63;
    int l16 = lane & 15, quad = lane >> 4;
    int rowl = rt * 64 + w * 16 + l16;
    int rid = b * 2048 + rowl;
    float step = stepp[0];
    float4 c4 = charges4[rid];
    float rx = step * c4.x, ry = step * c4.y, rz = step * c4.z, rw = step * c4.w;
    const ushort_t* crow = compat + (long)rid * 2048;
    f32x4 acc[4] = {};
    float Ss = 0.f;
    int mend = rt * 64 + 64;
    for (int kc = 0; kc < mend; kc += 32) {
        int mk = kc + quad * 8;
        u16x8 cv = *reinterpret_cast<const u16x8*>(crow + mk);
        const float4* chp = charges4 + b * 2048 + mk;
        bf16x8 pf;
#pragma unroll
        for (int j = 0; j < 8; j++) {
            float4 ch = chp[j];
            float sg = 1.f + rx * ch.x + ry * ch.y + rz * ch.z + rw * ch.w;
            float p = (mk + j <= rowl) ? __expf(bf2f(cv[j]) * sg) : 0.f;
            Ss += p;
            pf[j] = f2bf(p);
        }
        bf16x8 vf[4];
#pragma unroll
        for (int f = 0; f < 4; f++)
            vf[f] = *reinterpret_cast<const bf16x8*>(VbT + (long)(f * 16 + l16) * 8192 + b * 2048 + mk);
#pragma unroll
        for (int f = 0; f < 4; f++)
            acc[f] = __builtin_amdgcn_mfma_f32_16x16x32_bf16(pf, vf[f], acc[f], 0, 0, 0);
    }
    Ss += __shfl_xor(Ss, 16);
    Ss += __shfl_xor(Ss, 32);
    if (quad == 0) sL[w][l16] = fmaxf(Ss, 1e-30f);
    __syncthreads();
    float Sinv[4];
#pragma unroll
    for (int rr = 0; rr < 4; rr++) Sinv[rr] = 1.f / sL[w][quad * 4 + rr];
#pragma unroll
    for (int f = 0; f < 4; f++)
#pragma unroll
        for (int rr = 0; rr < 4; rr++) {
            int row = rt * 64 + w * 16 + quad * 4 + rr;
            Oacc[(long)(b * 2048 + row) * 64 + f * 16 + l16] = acc[f][rr] * Sinv[rr];
        }
}

// ---------------- out = (Oacc @ Wo^T) * 0.1, fp32 store
__global__ __launch_bounds__(256) void k_oproj(const float* __restrict__ Oacc,
                                               const float* __restrict__ Wo,
                                               float* __restrict__ out) {
    int mt = blockIdx.x & 63, nt = blockIdx.x >> 6;
    int wave = threadIdx.x >> 6, lane = threadIdx.x & 63;
    int wm = wave >> 1, wn = wave & 1;
    int l16 = lane & 15, quad = lane >> 4;
    int row0 = mt * 128 + wm * 64;
    int col0 = nt * 128 + wn * 64;
    f32x4 acc[4][4] = {};
#pragma unroll
    for (int kc = 0; kc < 64; kc += 32) {
        int ko = kc + quad * 8;
        bf16x8 af[4], bfm[4];
#pragma unroll
        for (int f = 0; f < 4; f++) af[f] = ld8f(Oacc + (long)(row0 + f * 16 + l16) * 64 + ko);
#pragma unroll
        for (int f = 0; f < 4; f++) bfm[f] = ld8f(Wo + (long)(col0 + f * 16 + l16) * 64 + ko);
#pragma unroll
        for (int i = 0; i < 4; i++)
#pragma unroll
            for (int j = 0; j < 4; j++)
                acc[i][j] = __builtin_amdgcn_mfma_f32_16x16x32_bf16(af[i], bfm[j], acc[i][j], 0, 0, 0);
    }
#pragma unroll
    for (int i = 0; i < 4; i++)
#pragma unroll
        for (int j = 0; j < 4; j++)
#pragma unroll
            for (int rr = 0; rr < 4; rr++) {
                long rowg = row0 + i * 16 + quad * 4 + rr;
                int colg = col0 + j * 16 + l16;
                out[rowg * 1024 + colg] = acc[i][j][rr] * 0.1f;
            }
}

extern "C" void kernel_launch(void* const* d_in, const int* in_sizes, int n_in,
                              void* d_out, int out_size, void* d_ws, size_t ws_size,
                              hipStream_t stream) {
    const float* hidden = (const float*)d_in[0];
    const float* W1 = (const float*)d_in[1];
    const float* b1 = (const float*)d_in[2];
    const float* W2 = (const float*)d_in[3];
    const float* b2 = (const float*)d_in[4];
    const float* Wq = (const float*)d_in[5];
    const float* Wk = (const float*)d_in[6];
    const float* Wc = (const float*)d_in[7];
    const float* bc = (const float*)d_in[8];
    const float* Wv = (const float*)d_in[9];
    const float* Wo = (const float*)d_in[10];
    const float* stepp = (const float*)d_in[11];
    const float* decayp = (const float*)d_in[12];

    char* ws = (char*)d_ws;
    size_t off = 0;
    auto alloc = [&](size_t bytes) {
        void* p = ws + off;
        off += (bytes + 255) & ~(size_t)255;
        return p;
    };
    ushort_t* compat = (ushort_t*)alloc(8192UL * 2048 * 2);  // 32 MiB bf16
    float* Ff = (float*)alloc(8192UL * 64 * 4);              // 2 MiB
    ushort_t* Qb = (ushort_t*)alloc(8192UL * 64 * 2);
    ushort_t* Kb = (ushort_t*)alloc(8192UL * 64 * 2);
    ushort_t* VbT = (ushort_t*)alloc(64UL * 8192 * 2);
    float* Oacc = (float*)alloc(8192UL * 64 * 4);
    float4* charges4 = (float4*)alloc(8192UL * 16);
    float* charge0 = (float*)alloc(8192UL * 4);
    float* Lrow = (float*)alloc(8192UL * 4);
    float* received = (float*)alloc(8192UL * 4);
    (void)ws_size; (void)in_sizes; (void)n_in; (void)out_size;

    k_fv<<<512, 256, 0, stream>>>(hidden, W1, Wv, Ff, VbT);
    k_feat<<<256, 256, 0, stream>>>(Ff, b1, W2, b2, Wq, Wk, Wc, bc, Qb, Kb, charge0, received);
    k_compat<<<544, 256, 0, stream>>>(Qb, Kb, compat);

    k_rowstats<0><<<2048, 256, 0, stream>>>(compat, charges4, stepp, Lrow);
    k_colsum<0><<<544, 256, 0, stream>>>(compat, charges4, stepp, Lrow, received);
    k_charge<1><<<32, 256, 0, stream>>>(received, charge0, charges4, decayp);

    k_rowstats<1><<<2048, 256, 0, stream>>>(compat, charges4, stepp, Lrow);
    k_colsum<1><<<544, 256, 0, stream>>>(compat, charges4, stepp, Lrow, received);
    k_charge<2><<<32, 256, 0, stream>>>(received, charge0, charges4, decayp);

    k_rowstats<2><<<2048, 256, 0, stream>>>(compat, charges4, stepp, Lrow);
    k_colsum<2><<<544, 256, 0, stream>>>(compat, charges4, stepp, Lrow, received);
    k_charge<3><<<32, 256, 0, stream>>>(received, charge0, charges4, decayp);

    k_rowstats<3><<<2048, 256, 0, stream>>>(compat, charges4, stepp, Lrow);
    k_colsum<3><<<544, 256, 0, stream>>>(compat, charges4, stepp, Lrow, received);
    k_charge<4><<<32, 256, 0, stream>>>(received, charge0, charges4, decayp);

    k_pv<<<128, 256, 0, stream>>>(compat, charges4, stepp, VbT, Oacc);
    k_oproj<<<512, 256, 0, stream>>>(Oacc, Wo, (float*)d_out);
}

// Round 5
// 320.362 us; speedup vs baseline: 1.5030x; 1.3753x over previous
//
#include <hip/hip_runtime.h>
#include <hip/hip_bf16.h>

typedef unsigned short ushort_t;
typedef short bf16x8 __attribute__((ext_vector_type(8)));
typedef ushort_t u16x8 __attribute__((ext_vector_type(8)));
typedef float f32x4 __attribute__((ext_vector_type(4)));

#define DEV static __device__ __forceinline__

DEV float bf2f(ushort_t u) { unsigned v = ((unsigned)u) << 16; float f; __builtin_memcpy(&f, &v, 4); return f; }
DEV short f2bf(float x) { __hip_bfloat16 h = __float2bfloat16(x); short s; __builtin_memcpy(&s, &h, 2); return s; }
DEV float sigm(float x) { return 1.0f / (1.0f + __expf(-x)); }

// load 8 consecutive fp32 and convert to a bf16x8 MFMA fragment
DEV bf16x8 ld8f(const float* __restrict__ p) {
    float4 a0 = *reinterpret_cast<const float4*>(p);
    float4 a1 = *reinterpret_cast<const float4*>(p + 4);
    bf16x8 t;
    t[0] = f2bf(a0.x); t[1] = f2bf(a0.y); t[2] = f2bf(a0.z); t[3] = f2bf(a0.w);
    t[4] = f2bf(a1.x); t[5] = f2bf(a1.y); t[6] = f2bf(a1.z); t[7] = f2bf(a1.w);
    return t;
}

// ---------------- K1: 16-row tiles: Ff[8192][64] = hidden@W1^T (fp32), VbT[64][8192] = (hidden@Wv^T)^T bf16
__global__ __launch_bounds__(256) void k_fv(const float* __restrict__ h,
        const float* __restrict__ W1, const float* __restrict__ Wv,
        float* __restrict__ Ff, ushort_t* __restrict__ VbT) {
    int m0 = blockIdx.x * 16;
    int wave = threadIdx.x >> 6, lane = threadIdx.x & 63;
    int l16 = lane & 15, quad = lane >> 4;
    const float* B = (wave < 2) ? W1 : Wv;
    int cb = (wave & 1) * 32;
    f32x4 acc[2] = {};
    const float* arow = h + (long)(m0 + l16) * 1024;
    const float* brow0 = B + (long)(cb + l16) * 1024;
    const float* brow1 = B + (long)(cb + 16 + l16) * 1024;
    for (int kc = 0; kc < 1024; kc += 32) {
        int ko = kc + quad * 8;
        bf16x8 af = ld8f(arow + ko);
        bf16x8 b0 = ld8f(brow0 + ko);
        bf16x8 b1v = ld8f(brow1 + ko);
        acc[0] = __builtin_amdgcn_mfma_f32_16x16x32_bf16(af, b0, acc[0], 0, 0, 0);
        acc[1] = __builtin_amdgcn_mfma_f32_16x16x32_bf16(af, b1v, acc[1], 0, 0, 0);
    }
    bool isV = (wave >= 2);
#pragma unroll
    for (int c = 0; c < 2; c++)
#pragma unroll
        for (int rr = 0; rr < 4; rr++) {
            int row = m0 + quad * 4 + rr;
            int col = cb + c * 16 + l16;
            float v = acc[c][rr];
            if (!isV) Ff[row * 64 + col] = v;
            else VbT[(long)col * 8192 + row] = (ushort_t)f2bf(v);
        }
}

// ---------------- K2: gelu -> features -> Q,K,charge0; zero received. 256 blocks x 32 rows.
__global__ __launch_bounds__(256) void k_feat(const float* __restrict__ Ff,
        const float* __restrict__ b1, const float* __restrict__ W2, const float* __restrict__ b2,
        const float* __restrict__ Wq, const float* __restrict__ Wk,
        const float* __restrict__ Wc, const float* __restrict__ bc,
        ushort_t* __restrict__ Qb, ushort_t* __restrict__ Kb,
        float* __restrict__ charge0, float* __restrict__ received) {
    __shared__ float w2L[28 * 65], wqL[64 * 29], wkL[64 * 29], wcL[28], b2L[28];
    __shared__ float fL[4][64], featL[4][28];
    int tid = threadIdx.x;
    for (int i = tid; i < 28 * 64; i += 256) w2L[(i >> 6) * 65 + (i & 63)] = W2[i];
    for (int i = tid; i < 64 * 28; i += 256) {
        int r = i / 28, c = i - r * 28;
        wqL[r * 29 + c] = Wq[i];
        wkL[r * 29 + c] = Wk[i];
    }
    if (tid < 28) { wcL[tid] = Wc[tid]; b2L[tid] = b2[tid]; }
    __syncthreads();
    int w = tid >> 6, lane = tid & 63;
    float b1v = b1[lane];
    float bcv = bc[0];
    for (int it = 0; it < 8; it++) {
        int row = blockIdx.x * 32 + it * 4 + w;
        float x = Ff[row * 64 + lane] + b1v;
        fL[w][lane] = 0.5f * x * (1.0f + erff(x * 0.70710678118654752f));
        __syncthreads();
        if (lane < 28) {
            float s = b2L[lane];
#pragma unroll
            for (int j = 0; j < 64; j++) s += fL[w][j] * w2L[lane * 65 + j];
            featL[w][lane] = sigm(s);
        }
        __syncthreads();
        float q = 0.f, k = 0.f;
#pragma unroll
        for (int i = 0; i < 28; i++) {
            float fv = featL[w][i];
            q += fv * wqL[lane * 29 + i];
            k += fv * wkL[lane * 29 + i];
        }
        Qb[row * 64 + lane] = (ushort_t)f2bf(q * 0.125f);  // fold 1/sqrt(64)
        Kb[row * 64 + lane] = (ushort_t)f2bf(k);
        if (lane == 0) {
            float c = bcv;
#pragma unroll
            for (int i = 0; i < 28; i++) c += featL[w][i] * wcL[i];
            charge0[row] = sigm(c);
            received[row] = 0.f;
        }
        __syncthreads();
    }
}

DEV void tri_decode(int r, int& ti, int& tj) {
    int t = (int)((sqrtf(8.f * (float)r + 1.f) - 1.f) * 0.5f);
    while ((t + 1) * (t + 2) / 2 <= r) t++;
    while (t * (t + 1) / 2 > r) t--;
    ti = t;
    tj = r - t * (t + 1) / 2;
}

// ---------------- K3: compat[(b*2048+n)][m] = (Q/8)·K, causal 128x128 tiles, bf16 store
__global__ __launch_bounds__(256) void k_compat(const ushort_t* __restrict__ Qb,
                                                const ushort_t* __restrict__ Kb,
                                                ushort_t* __restrict__ compat) {
    int bid = blockIdx.x;
    int b = bid / 136, r = bid % 136, ti, tj;
    tri_decode(r, ti, tj);
    int wave = threadIdx.x >> 6, lane = threadIdx.x & 63;
    int l16 = lane & 15, quad = lane >> 4;
    int rbase = b * 2048 + ti * 128 + wave * 32;
    int cbase = b * 2048 + tj * 128;
    f32x4 acc[2][8] = {};
#pragma unroll
    for (int kc = 0; kc < 64; kc += 32) {
        int ko = kc + quad * 8;
        bf16x8 af[2], bf[8];
#pragma unroll
        for (int f = 0; f < 2; f++) af[f] = *reinterpret_cast<const bf16x8*>(Qb + (long)(rbase + f * 16 + l16) * 64 + ko);
#pragma unroll
        for (int f = 0; f < 8; f++) bf[f] = *reinterpret_cast<const bf16x8*>(Kb + (long)(cbase + f * 16 + l16) * 64 + ko);
#pragma unroll
        for (int i = 0; i < 2; i++)
#pragma unroll
            for (int j = 0; j < 8; j++)
                acc[i][j] = __builtin_amdgcn_mfma_f32_16x16x32_bf16(af[i], bf[j], acc[i][j], 0, 0, 0);
    }
    int colt = tj * 128;
#pragma unroll
    for (int i = 0; i < 2; i++)
#pragma unroll
        for (int j = 0; j < 8; j++)
#pragma unroll
            for (int rr = 0; rr < 4; rr++) {
                long rowg = rbase + i * 16 + quad * 4 + rr;
                int col = colt + j * 16 + l16;
                compat[rowg * 2048 + col] = (ushort_t)f2bf(acc[i][j][rr]);
            }
}

// ---------------- pass A: Lrow[n] = sum_m<=n exp(compat*sigma)
template <int T>
__global__ __launch_bounds__(256) void k_rowstats(const ushort_t* __restrict__ compat,
        const float4* __restrict__ charges4, const float* __restrict__ stepp,
        float* __restrict__ Lrow) {
    int wave = threadIdx.x >> 6, lane = threadIdx.x & 63;
    int id = blockIdx.x * 4 + wave;
    int n = id & 2047;
    int colbase = id & ~2047;
    float step = stepp[0];
    float rx = 0.f, ry = 0.f, rz = 0.f, rw = 0.f;
    if (T > 0) {
        float4 c4 = charges4[id];
        rx = step * c4.x;
        if (T > 1) ry = step * c4.y;
        if (T > 2) rz = step * c4.z;
        if (T > 3) rw = step * c4.w;
    }
    const ushort_t* crow = compat + (long)id * 2048;
    float S = 0.f;
    for (int m = lane; m <= n; m += 64) {
        float c = bf2f(crow[m]);
        float sg = 1.f;
        if (T > 0) {
            float4 ch = charges4[colbase + m];
            sg += rx * ch.x;
            if (T > 1) sg += ry * ch.y;
            if (T > 2) sg += rz * ch.z;
            if (T > 3) sg += rw * ch.w;
        }
        S += __expf(c * sg);
    }
#pragma unroll
    for (int off = 32; off > 0; off >>= 1) S += __shfl_down(S, off);
    if (lane == 0) Lrow[id] = fmaxf(S, 1e-30f);
}

// ---------------- pass B: received[m] += sum_n attn[n][m]; rows split x2 across blocks
template <int T>
__global__ __launch_bounds__(256) void k_colsum(const ushort_t* __restrict__ compat,
        const float4* __restrict__ charges4, const float* __restrict__ stepp,
        const float* __restrict__ Lrow, float* __restrict__ received) {
    __shared__ float sums[128];
    int bid = blockIdx.x;
    int b = bid / 272, rem = bid % 272;
    int z = rem & 1, r = rem >> 1, ti, tj;
    tri_decode(r, ti, tj);
    int tid = threadIdx.x;
    int ml = tid & 127, half = tid >> 7;
    int m = tj * 128 + ml;
    int mid = b * 2048 + m;
    float step = stepp[0];
    float cx = 0.f, cy = 0.f, cz = 0.f, cw = 0.f;
    if (T > 0) {
        float4 cm = charges4[mid];
        cx = step * cm.x;
        if (T > 1) cy = step * cm.y;
        if (T > 2) cz = step * cm.z;
        if (T > 3) cw = step * cm.w;
    }
    float acc = 0.f;
    bool diag = (ti == tj);
    for (int k = 0; k < 32; k++) {
        int nl = z * 64 + half + 2 * k;
        int n = ti * 128 + nl;
        int nid = b * 2048 + n;
        float Li = 1.0f / Lrow[nid];
        float sg = 1.f;
        if (T > 0) {
            float4 cn = charges4[nid];
            sg += cx * cn.x;
            if (T > 1) sg += cy * cn.y;
            if (T > 2) sg += cz * cn.z;
            if (T > 3) sg += cw * cn.w;
        }
        float c = bf2f(compat[(long)nid * 2048 + m]);
        float p = __expf(c * sg) * Li;
        if (!diag || m <= n) acc += p;
    }
    if (half == 0) sums[ml] = acc;
    __syncthreads();
    if (half == 1) sums[ml] += acc;
    __syncthreads();
    if (tid < 128) atomicAdd(&received[b * 2048 + tj * 128 + tid], sums[tid]);
}

// ---------------- charge update t (writes charges4 component T-1; re-zeroes received)
template <int T>
__global__ void k_charge(float* __restrict__ received, const float* __restrict__ charge0,
                         float4* __restrict__ charges4, const float* __restrict__ decayp) {
    int i = blockIdx.x * 256 + threadIdx.x;
    if (i >= 8192) return;
    float decay = decayp[0];
    float rcv = received[i];
    float sg = 1.0f / (1.0f + __expf(1.0f - rcv));
    float prev = (T == 1) ? charge0[i] : ((const float*)&charges4[i])[T - 2];
    ((float*)&charges4[i])[T - 1] = prev * (1.f - decay * sg);
    received[i] = 0.f;
}

// ---------------- final attention + PV, self-normalizing.
// block = (batch, 16-row tile); 4 waves split the column range in interleaved 32-col chunks;
// partial accumulators + row-sums combined through LDS. 512 blocks, no atomics.
__global__ __launch_bounds__(256) void k_pv(const ushort_t* __restrict__ compat,
        const float4* __restrict__ charges4, const float* __restrict__ stepp,
        const ushort_t* __restrict__ VbT, float* __restrict__ Oacc) {
    __shared__ float accL[3][64][17];
    __shared__ float ssL[4][16];
    int bid = blockIdx.x;
    int b = bid & 3, rtile = 127 - (bid >> 2);  // big tiles dispatched first
    int r0 = rtile * 16;
    int w = threadIdx.x >> 6, lane = threadIdx.x & 63;
    int l16 = lane & 15, quad = lane >> 4;
    int rowl = r0 + l16;             // this lane's A-fragment row (within batch)
    int rid = b * 2048 + rowl;
    float step = stepp[0];
    float4 c4 = charges4[rid];
    float rx = step * c4.x, ry = step * c4.y, rz = step * c4.z, rw = step * c4.w;
    const ushort_t* crow = compat + (long)rid * 2048;
    f32x4 acc[4] = {};
    float Ss = 0.f;
    int colend = r0 + 16;
    for (int kc = w * 32; kc < colend; kc += 128) {
        int mk = kc + quad * 8;
        u16x8 cv = *reinterpret_cast<const u16x8*>(crow + mk);
        const float4* chp = charges4 + b * 2048 + mk;
        bf16x8 pf;
#pragma unroll
        for (int j = 0; j < 8; j++) {
            float4 ch = chp[j];
            float sg = 1.f + rx * ch.x + ry * ch.y + rz * ch.z + rw * ch.w;
            float p = (mk + j <= rowl) ? __expf(bf2f(cv[j]) * sg) : 0.f;
            Ss += p;
            pf[j] = f2bf(p);
        }
        bf16x8 vf[4];
#pragma unroll
        for (int f = 0; f < 4; f++)
            vf[f] = *reinterpret_cast<const bf16x8*>(VbT + (long)(f * 16 + l16) * 8192 + b * 2048 + mk);
#pragma unroll
        for (int f = 0; f < 4; f++)
            acc[f] = __builtin_amdgcn_mfma_f32_16x16x32_bf16(pf, vf[f], acc[f], 0, 0, 0);
    }
    // per-wave row-sum over the 4 quads (row = l16)
    Ss += __shfl_xor(Ss, 16);
    Ss += __shfl_xor(Ss, 32);
    if (quad == 0) ssL[w][l16] = Ss;
    if (w > 0) {
#pragma unroll
        for (int f = 0; f < 4; f++)
#pragma unroll
            for (int rr = 0; rr < 4; rr++)
                accL[w - 1][lane][f * 4 + rr] = acc[f][rr];
    }
    __syncthreads();
    if (w == 0) {
#pragma unroll
        for (int f = 0; f < 4; f++)
#pragma unroll
            for (int rr = 0; rr < 4; rr++)
                acc[f][rr] += accL[0][lane][f * 4 + rr] + accL[1][lane][f * 4 + rr] + accL[2][lane][f * 4 + rr];
        float Sinv[4];
#pragma unroll
        for (int rr = 0; rr < 4; rr++) {
            int idx = quad * 4 + rr;
            float st = ssL[0][idx] + ssL[1][idx] + ssL[2][idx] + ssL[3][idx];
            Sinv[rr] = 1.f / fmaxf(st, 1e-30f);
        }
#pragma unroll
        for (int f = 0; f < 4; f++)
#pragma unroll
            for (int rr = 0; rr < 4; rr++) {
                int row = r0 + quad * 4 + rr;
                Oacc[(long)(b * 2048 + row) * 64 + f * 16 + l16] = acc[f][rr] * Sinv[rr];
            }
    }
}

// ---------------- out = (Oacc @ Wo^T) * 0.1, fp32 store
__global__ __launch_bounds__(256) void k_oproj(const float* __restrict__ Oacc,
                                               const float* __restrict__ Wo,
                                               float* __restrict__ out) {
    int mt = blockIdx.x & 63, nt = blockIdx.x >> 6;
    int wave = threadIdx.x >> 6, lane = threadIdx.x & 63;
    int wm = wave >> 1, wn = wave & 1;
    int l16 = lane & 15, quad = lane >> 4;
    int row0 = mt * 128 + wm * 64;
    int col0 = nt * 128 + wn * 64;
    f32x4 acc[4][4] = {};
#pragma unroll
    for (int kc = 0; kc < 64; kc += 32) {
        int ko = kc + quad * 8;
        bf16x8 af[4], bfm[4];
#pragma unroll
        for (int f = 0; f < 4; f++) af[f] = ld8f(Oacc + (long)(row0 + f * 16 + l16) * 64 + ko);
#pragma unroll
        for (int f = 0; f < 4; f++) bfm[f] = ld8f(Wo + (long)(col0 + f * 16 + l16) * 64 + ko);
#pragma unroll
        for (int i = 0; i < 4; i++)
#pragma unroll
            for (int j = 0; j < 4; j++)
                acc[i][j] = __builtin_amdgcn_mfma_f32_16x16x32_bf16(af[i], bfm[j], acc[i][j], 0, 0, 0);
    }
#pragma unroll
    for (int i = 0; i < 4; i++)
#pragma unroll
        for (int j = 0; j < 4; j++)
#pragma unroll
            for (int rr = 0; rr < 4; rr++) {
                long rowg = row0 + i * 16 + quad * 4 + rr;
                int colg = col0 + j * 16 + l16;
                out[rowg * 1024 + colg] = acc[i][j][rr] * 0.1f;
            }
}

extern "C" void kernel_launch(void* const* d_in, const int* in_sizes, int n_in,
                              void* d_out, int out_size, void* d_ws, size_t ws_size,
                              hipStream_t stream) {
    const float* hidden = (const float*)d_in[0];
    const float* W1 = (const float*)d_in[1];
    const float* b1 = (const float*)d_in[2];
    const float* W2 = (const float*)d_in[3];
    const float* b2 = (const float*)d_in[4];
    const float* Wq = (const float*)d_in[5];
    const float* Wk = (const float*)d_in[6];
    const float* Wc = (const float*)d_in[7];
    const float* bc = (const float*)d_in[8];
    const float* Wv = (const float*)d_in[9];
    const float* Wo = (const float*)d_in[10];
    const float* stepp = (const float*)d_in[11];
    const float* decayp = (const float*)d_in[12];

    char* ws = (char*)d_ws;
    size_t off = 0;
    auto alloc = [&](size_t bytes) {
        void* p = ws + off;
        off += (bytes + 255) & ~(size_t)255;
        return p;
    };
    ushort_t* compat = (ushort_t*)alloc(8192UL * 2048 * 2);  // 32 MiB bf16
    float* Ff = (float*)alloc(8192UL * 64 * 4);              // 2 MiB
    ushort_t* Qb = (ushort_t*)alloc(8192UL * 64 * 2);
    ushort_t* Kb = (ushort_t*)alloc(8192UL * 64 * 2);
    ushort_t* VbT = (ushort_t*)alloc(64UL * 8192 * 2);
    float* Oacc = (float*)alloc(8192UL * 64 * 4);
    float4* charges4 = (float4*)alloc(8192UL * 16);
    float* charge0 = (float*)alloc(8192UL * 4);
    float* Lrow = (float*)alloc(8192UL * 4);
    float* received = (float*)alloc(8192UL * 4);
    (void)ws_size; (void)in_sizes; (void)n_in; (void)out_size;

    k_fv<<<512, 256, 0, stream>>>(hidden, W1, Wv, Ff, VbT);
    k_feat<<<256, 256, 0, stream>>>(Ff, b1, W2, b2, Wq, Wk, Wc, bc, Qb, Kb, charge0, received);
    k_compat<<<544, 256, 0, stream>>>(Qb, Kb, compat);

    k_rowstats<0><<<2048, 256, 0, stream>>>(compat, charges4, stepp, Lrow);
    k_colsum<0><<<1088, 256, 0, stream>>>(compat, charges4, stepp, Lrow, received);
    k_charge<1><<<32, 256, 0, stream>>>(received, charge0, charges4, decayp);

    k_rowstats<1><<<2048, 256, 0, stream>>>(compat, charges4, stepp, Lrow);
    k_colsum<1><<<1088, 256, 0, stream>>>(compat, charges4, stepp, Lrow, received);
    k_charge<2><<<32, 256, 0, stream>>>(received, charge0, charges4, decayp);

    k_rowstats<2><<<2048, 256, 0, stream>>>(compat, charges4, stepp, Lrow);
    k_colsum<2><<<1088, 256, 0, stream>>>(compat, charges4, stepp, Lrow, received);
    k_charge<3><<<32, 256, 0, stream>>>(received, charge0, charges4, decayp);

    k_rowstats<3><<<2048, 256, 0, stream>>>(compat, charges4, stepp, Lrow);
    k_colsum<3><<<1088, 256, 0, stream>>>(compat, charges4, stepp, Lrow, received);
    k_charge<4><<<32, 256, 0, stream>>>(received, charge0, charges4, decayp);

    k_pv<<<512, 256, 0, stream>>>(compat, charges4, stepp, VbT, Oacc);
    k_oproj<<<512, 256, 0, stream>>>(Oacc, Wo, (float*)d_out);
}